// Round 2
// baseline (804.172 us; speedup 1.0000x reference)
//
#include <hip/hip_runtime.h>
#include <hip/hip_bf16.h>
#include <cstdint>

typedef __bf16 bf16x8 __attribute__((ext_vector_type(8)));
typedef __bf16 bf16x4 __attribute__((ext_vector_type(4)));
typedef short  short4v __attribute__((ext_vector_type(4)));
typedef _Float16 f16x4 __attribute__((ext_vector_type(4)));
typedef float f32x4 __attribute__((ext_vector_type(4)));

union U128 { uint4 u; __bf16 h[8]; };
union U64  { uint2 u; __bf16 h[4]; };
union PV4  { uint2 u; bf16x4 b; short4v s; f16x4 f; };

#define DMODEL 1024
#define NHEAD  16
#define DHEAD  64

// ---- 16x16x16 MFMA selection for the PV step (P/V as 4x16-bit per lane) ----
#if __has_builtin(__builtin_amdgcn_mfma_f32_16x16x16_bf16)
#define PV_F16 0
__device__ __forceinline__ f32x4 mfma16(PV4 a, PV4 b, f32x4 c) {
  return __builtin_amdgcn_mfma_f32_16x16x16_bf16(a.b, b.b, c, 0, 0, 0);
}
#elif __has_builtin(__builtin_amdgcn_mfma_f32_16x16x16bf16_1k)
#define PV_F16 0
__device__ __forceinline__ f32x4 mfma16(PV4 a, PV4 b, f32x4 c) {
  return __builtin_amdgcn_mfma_f32_16x16x16bf16_1k(a.s, b.s, c, 0, 0, 0);
}
#else
#define PV_F16 1
__device__ __forceinline__ f32x4 mfma16(PV4 a, PV4 b, f32x4 c) {
  return __builtin_amdgcn_mfma_f32_16x16x16f16(a.f, b.f, c, 0, 0, 0);
}
#endif

__device__ __forceinline__ uint16_t pv_bits(__bf16 v) {
#if PV_F16
  union { _Float16 f; uint16_t u; } x; x.f = (_Float16)(float)v; return x.u;
#else
  union { __bf16 b; uint16_t u; } x; x.b = v; return x.u;
#endif
}

__device__ __forceinline__ PV4 pack4(float a, float b, float c, float d) {
  PV4 r;
#if PV_F16
  r.f = (f16x4){(_Float16)a, (_Float16)b, (_Float16)c, (_Float16)d};
#else
  r.b = (bf16x4){(__bf16)a, (__bf16)b, (__bf16)c, (__bf16)d};
#endif
  return r;
}

__device__ __forceinline__ void async_copy16(const void* g, void* l) {
  __builtin_amdgcn_global_load_lds(
      (const __attribute__((address_space(1))) void*)g,
      (__attribute__((address_space(3))) void*)l, 16, 0, 0);
}

// ---------------- fused fp32 -> bf16 cast of two buffers ----------------
__global__ __launch_bounds__(256) void k_cast2(const float* __restrict__ a,
    const float* __restrict__ b, __bf16* __restrict__ da,
    __bf16* __restrict__ db, int n) {
  int i = (blockIdx.x * 256 + threadIdx.x) * 4;
  const float* s = a; __bf16* d = da;
  if (i >= n) { s = b; d = db; i -= n; }
  float4 v = *(const float4*)(s + i);
  U64 o;
  o.h[0] = (__bf16)v.x; o.h[1] = (__bf16)v.y;
  o.h[2] = (__bf16)v.z; o.h[3] = (__bf16)v.w;
  *(uint2*)(d + i) = o.u;
}

// ---------------- pack up to 3 fp32 bias vectors (n each) into dst ----------------
__global__ __launch_bounds__(256) void k_pack(float* __restrict__ dst,
    const float* __restrict__ s0, const float* __restrict__ s1,
    const float* __restrict__ s2, int n) {
  int i = blockIdx.x * 256 + threadIdx.x;
  if (i < n) dst[i] = s0[i];
  else if (i < 2 * n) dst[i] = s1[i - n];
  else if (i < 3 * n) dst[i] = s2[i - 2 * n];
}

// ------------- batched 32x32 transpose + cast: src[z][R][C] f32 -> dst[z][C][R] bf16 -------------
__global__ __launch_bounds__(256) void k_transpose(const float* __restrict__ src,
    __bf16* __restrict__ dst, int R, int C) {
  __shared__ __bf16 tile[32][33];
  src += (size_t)blockIdx.z * R * C;
  dst += (size_t)blockIdx.z * R * C;
  int c0 = blockIdx.x * 32, r0 = blockIdx.y * 32;
  int tx = threadIdx.x & 31, ty = threadIdx.x >> 5;
  for (int i = ty; i < 32; i += 8)
    tile[i][tx] = (__bf16)src[(size_t)(r0 + i) * C + (c0 + tx)];
  __syncthreads();
  for (int i = ty; i < 32; i += 8)
    dst[(size_t)(c0 + i) * R + (r0 + tx)] = tile[tx][i];
}

// ------------- 3-source per-head transpose: srcN[16][R][C] f32 -> dst[z][C][R] bf16, z=src*16+head
__global__ __launch_bounds__(256) void k_transpose3(const float* __restrict__ s0,
    const float* __restrict__ s1, const float* __restrict__ s2,
    __bf16* __restrict__ dst, int R, int C) {
  __shared__ __bf16 tile[32][33];
  int z = blockIdx.z;
  const float* src = (z < 16) ? s0 : (z < 32) ? s1 : s2;
  src += (size_t)(z & 15) * R * C;
  dst += (size_t)z * R * C;
  int c0 = blockIdx.x * 32, r0 = blockIdx.y * 32;
  int tx = threadIdx.x & 31, ty = threadIdx.x >> 5;
  for (int i = ty; i < 32; i += 8)
    tile[i][tx] = (__bf16)src[(size_t)(r0 + i) * C + (c0 + tx)];
  __syncthreads();
  for (int i = ty; i < 32; i += 8)
    dst[(size_t)(c0 + i) * R + (r0 + tx)] = tile[tx][i];
}

// ---------------- bf16 TN GEMM: C[M,N] = A[M,K] * Bt[N,K]^T + bias ----------------
// 128x128 tile, BK=64, global_load_lds staging, 16B-granule XOR swizzle.
template<bool RELU, typename OutT>
__global__ __launch_bounds__(256, 3) void k_gemm(const __bf16* __restrict__ A,
    const __bf16* __restrict__ Bt, const float* __restrict__ bias,
    OutT* __restrict__ C, int M, int N, int K) {
  __shared__ __bf16 As[128][64];
  __shared__ __bf16 Bs[128][64];
  const int m0 = blockIdx.y * 128, n0 = blockIdx.x * 128;
  const int t = threadIdx.x;
  const int wave = t >> 6, lane = t & 63;
  const int wm = (wave & 1) * 64, wn = (wave >> 1) * 64;
  const int lrow = lane & 15, quad = lane >> 4;
  const int r8 = lane >> 3;
  const int gG = (lane & 7) ^ (r8 & 7);
  const __bf16* Ap[4]; const __bf16* Bp[4];
  __bf16* lA[4]; __bf16* lB[4];
  for (int j = 0; j < 4; j++) {
    int rr = wave * 8 + j * 32 + r8;
    Ap[j] = A  + (size_t)(m0 + rr) * K + gG * 8;
    Bp[j] = Bt + (size_t)(n0 + rr) * K + gG * 8;
    lA[j] = &As[wave * 8 + j * 32][0];
    lB[j] = &Bs[wave * 8 + j * 32][0];
  }
  f32x4 acc[4][4] = {};
  for (int k0 = 0; k0 < K; k0 += 64) {
    __syncthreads();
    for (int j = 0; j < 4; j++) {
      async_copy16(Ap[j] + k0, lA[j]);
      async_copy16(Bp[j] + k0, lB[j]);
    }
    __syncthreads();
    for (int ks = 0; ks < 2; ks++) {
      bf16x8 af[4], bfv[4];
      for (int i = 0; i < 4; i++) {
        int ra = wm + i * 16 + lrow, rb = wn + i * 16 + lrow;
        af[i]  = *(const bf16x8*)&As[ra][(((ks * 4 + quad) ^ (ra & 7))) * 8];
        bfv[i] = *(const bf16x8*)&Bs[rb][(((ks * 4 + quad) ^ (rb & 7))) * 8];
      }
      for (int mi = 0; mi < 4; mi++)
        for (int ni = 0; ni < 4; ni++)
          acc[mi][ni] = __builtin_amdgcn_mfma_f32_16x16x32_bf16(af[mi], bfv[ni], acc[mi][ni], 0, 0, 0);
    }
  }
  for (int ni = 0; ni < 4; ni++) {
    int col = n0 + wn + ni * 16 + lrow;
    float bv = bias[col];
    for (int mi = 0; mi < 4; mi++) {
      int row = m0 + wm + mi * 16 + quad * 4;
      for (int r = 0; r < 4; r++) {
        float v = acc[mi][ni][r] + bv;
        if (RELU) v = fmaxf(v, 0.f);
        C[(size_t)(row + r) * N + col] = (OutT)v;
      }
    }
  }
}

// ---------------- fused flash attention v3: 2 q-tiles/block, S^T trick, register PV ----------
// grid (Lq/128, B*H). Causal: block bx covers q-tiles (bx, NT-1-bx) — compute-balanced pairing,
// fully-masked sub-tiles skipped via wave-uniform branch. Cross: tiles (2bx, 2bx+1).
// Each wave: 16 q-rows per tile. Softmax in exp2 domain (scale*log2e folded into Q).
// vs 653us baseline: V^T frags hoisted across both f-tiles (Vt reads halved),
// l-sum cross-lane reduce deferred to epilogue (valid: alpha is uniform across
// the 4-lane group since pm is group-reduced and m_r stays group-uniform),
// s_setprio(1) around MFMA clusters (T5).
template<bool CAUSAL>
__global__ __launch_bounds__(256, 4) void k_attn(const __bf16* __restrict__ Q,
    const __bf16* __restrict__ Kg, const __bf16* __restrict__ Vg,
    float* __restrict__ O, int Lq, int Lk, int qs, int kvs) {
  __shared__ alignas(16) __bf16   Ks[2][64][72];
  __shared__ alignas(16) uint16_t Vt[2][64][72];   // [vd][k]
  const int t = threadIdx.x;
  const int wave = t >> 6, lane = t & 63;
  const int lrow = lane & 15, quad = lane >> 4;
  const int wm16 = wave * 16;
  int qt[2];
  if (CAUSAL) { qt[0] = blockIdx.x; qt[1] = gridDim.x * 2 - 1 - blockIdx.x; }
  else        { qt[0] = blockIdx.x * 2; qt[1] = qt[0] + 1; }
  const int b = blockIdx.y >> 4, h = blockIdx.y & 15;
  const __bf16* Qb = Q  + (size_t)b * Lq * qs  + h * DHEAD;
  const __bf16* Kb = Kg + (size_t)b * Lk * kvs + h * DHEAD;
  const __bf16* Vb = Vg + (size_t)b * Lk * kvs + h * DHEAD;
  // Q B-fragments, scale folded: 0.125 * log2(e) (softmax done in exp2 domain)
  const float qsc = 0.125f * 1.44269504f;
  bf16x8 qf[2][2];
  for (int f = 0; f < 2; f++)
    for (int ks = 0; ks < 2; ks++) {
      U128 u;
      u.u = *(const uint4*)(Qb + (size_t)(qt[f] * 64 + wm16 + lrow) * qs + ks * 32 + quad * 8);
      for (int j = 0; j < 8; j++) u.h[j] = (__bf16)((float)u.h[j] * qsc);
      qf[f][ks] = *(const bf16x8*)u.h;
    }
  const int nkt = CAUSAL ? (qt[1] + 1) : (Lk / 64);
  const int krow = t >> 3, kcol = (t & 7) * 8;
  const int vkk = t & 63;
  f32x4 acc_o[2][4] = {};       // O^T per frag: row vd=ni*16+quad*4+r, col q=lrow
  float m_r[2] = {-1e30f, -1e30f}, l_r[2] = {0.f, 0.f};
  uint4 ka, ka2, va, va2;
  ka  = *(const uint4*)(Kb + (size_t)krow * kvs + kcol);
  ka2 = *(const uint4*)(Kb + (size_t)(krow + 32) * kvs + kcol);
  va  = *(const uint4*)(Vb + (size_t)vkk * kvs + wave * 8);
  va2 = *(const uint4*)(Vb + (size_t)vkk * kvs + (wave + 4) * 8);
  int c = 0;
  for (int kt = 0; kt < nkt; kt++) {
    const int kn = (kt + 1 < nkt) ? (kt + 1) * 64 : kt * 64;
    uint4 na  = *(const uint4*)(Kb + (size_t)(kn + krow) * kvs + kcol);
    uint4 na2 = *(const uint4*)(Kb + (size_t)(kn + krow + 32) * kvs + kcol);
    uint4 nv  = *(const uint4*)(Vb + (size_t)(kn + vkk) * kvs + wave * 8);
    uint4 nv2 = *(const uint4*)(Vb + (size_t)(kn + vkk) * kvs + (wave + 4) * 8);
    *(uint4*)&Ks[c][krow][kcol]      = ka;
    *(uint4*)&Ks[c][krow + 32][kcol] = ka2;
    { U128 u; u.u = va;  for (int j = 0; j < 8; j++) Vt[c][wave * 8 + j][vkk] = pv_bits(u.h[j]); }
    { U128 u; u.u = va2; for (int j = 0; j < 8; j++) Vt[c][(wave + 4) * 8 + j][vkk] = pv_bits(u.h[j]); }
    __syncthreads();
    // V^T fragments are f-independent: read once per k-tile, reuse for both f.
    PV4 vfr[4][4];
    for (int ni = 0; ni < 4; ni++)
      for (int nb = 0; nb < 4; nb++)
        vfr[ni][nb].u = *(const uint2*)&Vt[c][ni * 16 + lrow][nb * 16 + quad * 4];
    for (int f = 0; f < 2; f++) {
      if (CAUSAL && kt > qt[f]) continue;   // wave-uniform: fully-masked sub-tile
      // S^T = K Q^T : C-layout row k=nb*16+quad*4+r, col q=lrow  (exp2 domain)
      f32x4 st[4] = {};
      __builtin_amdgcn_s_setprio(1);
      for (int ks = 0; ks < 2; ks++)
        for (int nb = 0; nb < 4; nb++) {
          bf16x8 kf = *(const bf16x8*)&Ks[c][nb * 16 + lrow][ks * 32 + quad * 8];
          st[nb] = __builtin_amdgcn_mfma_f32_16x16x32_bf16(kf, qf[f][ks], st[nb], 0, 0, 0);
        }
      __builtin_amdgcn_s_setprio(0);
      float pm = -1e30f;
      for (int nb = 0; nb < 4; nb++)
        for (int r = 0; r < 4; r++) {
          float s = st[nb][r];
          if (CAUSAL && kt == qt[f])
            if (nb * 16 + quad * 4 + r > wm16 + lrow) s = -1e30f;
          st[nb][r] = s;
          pm = fmaxf(pm, s);
        }
      pm = fmaxf(pm, __shfl_xor(pm, 16));
      pm = fmaxf(pm, __shfl_xor(pm, 32));
      float mn = fmaxf(m_r[f], pm);
      float alpha = exp2f(m_r[f] - mn);
      m_r[f] = mn;
      float rs = 0.f;
      PV4 pf[4];
      for (int nb = 0; nb < 4; nb++) {
        float p0 = exp2f(st[nb][0] - mn), p1 = exp2f(st[nb][1] - mn);
        float p2 = exp2f(st[nb][2] - mn), p3 = exp2f(st[nb][3] - mn);
        rs += (p0 + p1) + (p2 + p3);
        pf[nb] = pack4(p0, p1, p2, p3);
      }
      l_r[f] = l_r[f] * alpha + rs;             // per-lane partial; reduced in epilogue
      for (int ni = 0; ni < 4; ni++)
        for (int r = 0; r < 4; r++) acc_o[f][ni][r] *= alpha;
      // O^T += V^T P^T  (A = V^T frag from registers, B = P frag from registers)
      __builtin_amdgcn_s_setprio(1);
      for (int nb = 0; nb < 4; nb++)
        for (int ni = 0; ni < 4; ni++)
          acc_o[f][ni] = mfma16(vfr[ni][nb], pf[nb], acc_o[f][ni]);
      __builtin_amdgcn_s_setprio(0);
    }
    ka = na; ka2 = na2; va = nv; va2 = nv2;
    c ^= 1;
  }
  for (int f = 0; f < 2; f++) {
    float l = l_r[f];
    l += __shfl_xor(l, 16);
    l += __shfl_xor(l, 32);
    const float linv = 1.f / fmaxf(l, 1e-30f);
    float* orow = O + (size_t)b * Lq * DMODEL
                + (size_t)(qt[f] * 64 + wm16 + lrow) * DMODEL + h * DHEAD;
    for (int ni = 0; ni < 4; ni++) {
      float4 v = { acc_o[f][ni][0] * linv, acc_o[f][ni][1] * linv,
                   acc_o[f][ni][2] * linv, acc_o[f][ni][3] * linv };
      *(float4*)(orow + ni * 16 + quad * 4) = v;
    }
  }
}

// ---------------- residual(ResT + fp32) + LayerNorm -> OutT ----------------
template<typename ResT, typename OutT>
__global__ __launch_bounds__(256) void k_ln_add(const ResT* __restrict__ a,
    const float* __restrict__ bres, const float* __restrict__ g,
    const float* __restrict__ be, OutT* __restrict__ out) {
  __shared__ float red[2][4];
  const int r = blockIdx.x, t = threadIdx.x;
  const size_t base = (size_t)r * DMODEL + t * 4;
  float x[4];
  for (int i = 0; i < 4; i++) x[i] = (float)a[base + i] + bres[base + i];
  float s  = x[0] + x[1] + x[2] + x[3];
  float s2 = x[0]*x[0] + x[1]*x[1] + x[2]*x[2] + x[3]*x[3];
  for (int off = 32; off > 0; off >>= 1) {
    s  += __shfl_down(s, off);
    s2 += __shfl_down(s2, off);
  }
  if ((t & 63) == 0) { red[0][t >> 6] = s; red[1][t >> 6] = s2; }
  __syncthreads();
  s  = red[0][0] + red[0][1] + red[0][2] + red[0][3];
  s2 = red[1][0] + red[1][1] + red[1][2] + red[1][3];
  const float mean = s * (1.f / DMODEL);
  const float var  = s2 * (1.f / DMODEL) - mean * mean;
  const float rstd = rsqrtf(var + 1e-5f);
  for (int i = 0; i < 4; i++)
    out[base + i] = (OutT)((x[i] - mean) * rstd * g[t * 4 + i] + be[t * 4 + i]);
}

extern "C" void kernel_launch(void* const* d_in, const int* in_sizes, int n_in,
                              void* d_out, int out_size, void* d_ws, size_t ws_size,
                              hipStream_t stream) {
  (void)in_sizes; (void)n_in; (void)out_size; (void)ws_size;
  const float* dec   = (const float*)d_in[0];
  const float* enc   = (const float*)d_in[1];
  const float* m_wq  = (const float*)d_in[2];
  const float* m_bq  = (const float*)d_in[3];
  const float* m_wk  = (const float*)d_in[4];
  const float* m_bk  = (const float*)d_in[5];
  const float* m_wv  = (const float*)d_in[6];
  const float* m_bv  = (const float*)d_in[7];
  const float* c_wq  = (const float*)d_in[8];
  const float* c_bq  = (const float*)d_in[9];
  const float* c_wk  = (const float*)d_in[10];
  const float* c_bk  = (const float*)d_in[11];
  const float* c_wv  = (const float*)d_in[12];
  const float* c_bv  = (const float*)d_in[13];
  const float* ff_w1 = (const float*)d_in[14];
  const float* ff_b1 = (const float*)d_in[15];
  const float* ff_w2 = (const float*)d_in[16];
  const float* ff_b2 = (const float*)d_in[17];
  const float* ln1_g = (const float*)d_in[18];
  const float* ln1_b = (const float*)d_in[19];
  const float* ln2_g = (const float*)d_in[20];
  const float* ln2_b = (const float*)d_in[21];

  // workspace (136 MB):
  //  [0,16)   decB -> X1b          [16,32)  encB -> X2b
  //  [32,40)  WB weights (bf16); fp32 bias pack at +38MB
  //  [40,88)  QKV (self) | [40,72) KV (cross) + [72,88) Qc | [40,104) FF
  //  [104,136) AO (fp32)
  char* w = (char*)d_ws;
  __bf16* decB = (__bf16*)(w);
  __bf16* encB = (__bf16*)(w + (16ull << 20));
  __bf16* X1b  = decB;
  __bf16* X2b  = encB;
  __bf16* WB   = (__bf16*)(w + (32ull << 20));
  float*  BP   = (float*) (w + (38ull << 20));
  __bf16* QKV  = (__bf16*)(w + (40ull << 20));
  __bf16* KV   = (__bf16*)(w + (40ull << 20));
  __bf16* Qc   = (__bf16*)(w + (72ull << 20));
  __bf16* FF   = (__bf16*)(w + (40ull << 20));
  float*  AO   = (float*) (w + (104ull << 20));
  float* out = (float*)d_out;

  const int M = 8192, NTOK = M * DMODEL;
  dim3 blk(256);
  dim3 gT3(2, 32, 48);    // 3-source per-head weight transpose
  dim3 gA(8, 128);        // attention: 2 q-tiles per block
  dim3 gL(M);

  k_cast2<<<dim3(2 * NTOK / 1024), blk, 0, stream>>>(dec, enc, decB, encB, NTOK);

  // ---- masked self-attention: fused QKV projection (N=3072) ----
  k_transpose3<<<gT3, blk, 0, stream>>>(m_wq, m_wk, m_wv, WB, 1024, 64);
  k_pack<<<dim3(12), blk, 0, stream>>>(BP, m_bq, m_bk, m_bv, 1024);
  k_gemm<false, __bf16><<<dim3(24, 64), blk, 0, stream>>>(decB, WB, BP, QKV, M, 3072, 1024);
  k_attn<true><<<gA, blk, 0, stream>>>(QKV, QKV + 1024, QKV + 2048, AO, 1024, 1024, 3072, 3072);
  k_ln_add<float, __bf16><<<gL, blk, 0, stream>>>(dec, AO, ln1_g, ln1_b, X1b);  // decB dead

  // ---- cross-attention: fused KV (N=2048, enc) + Q (X1b) ----
  k_transpose3<<<gT3, blk, 0, stream>>>(c_wk, c_wv, c_wq, WB, 1024, 64);
  k_pack<<<dim3(8), blk, 0, stream>>>(BP, c_bk, c_bv, c_bv, 1024);
  k_gemm<false, __bf16><<<dim3(16, 64), blk, 0, stream>>>(encB, WB, BP, KV, M, 2048, 1024);
  k_gemm<false, __bf16><<<dim3(8, 64), blk, 0, stream>>>(X1b, WB + (2 << 20), c_bq, Qc, M, 1024, 1024);
  k_attn<false><<<gA, blk, 0, stream>>>(Qc, KV, KV + 1024, AO, 1024, 1024, 1024, 2048);
  k_ln_add<__bf16, __bf16><<<gL, blk, 0, stream>>>(X1b, AO, ln2_g, ln2_b, X2b);  // encB dead

  // ---- FFN (QKV/KV/Qc dead -> FF overlays [40,104)) ----
  k_transpose<<<dim3(128, 32, 1), blk, 0, stream>>>(ff_w1, WB, 1024, 4096);
  k_gemm<true, __bf16><<<dim3(32, 64), blk, 0, stream>>>(X2b, WB, ff_b1, FF, M, 4096, 1024);
  k_transpose<<<dim3(32, 128, 1), blk, 0, stream>>>(ff_w2, WB, 4096, 1024);
  k_gemm<false, float><<<dim3(8, 64), blk, 0, stream>>>(FF, WB, ff_b2, AO, M, 1024, 4096);
  k_ln_add<__bf16, float><<<gL, blk, 0, stream>>>(X2b, AO, ln2_g, ln2_b, out);
}

// Round 3
// 725.096 us; speedup vs baseline: 1.1091x; 1.1091x over previous
//
#include <hip/hip_runtime.h>
#include <hip/hip_bf16.h>
#include <cstdint>

typedef __bf16 bf16x8 __attribute__((ext_vector_type(8)));
typedef __bf16 bf16x4 __attribute__((ext_vector_type(4)));
typedef short  short4v __attribute__((ext_vector_type(4)));
typedef _Float16 f16x4 __attribute__((ext_vector_type(4)));
typedef float f32x4 __attribute__((ext_vector_type(4)));

union U128 { uint4 u; __bf16 h[8]; };
union U64  { uint2 u; __bf16 h[4]; };
union PV4  { uint2 u; bf16x4 b; short4v s; f16x4 f; };

#define DMODEL 1024
#define NHEAD  16
#define DHEAD  64

// ---- 16x16x16 MFMA selection for the PV step (P/V as 4x16-bit per lane) ----
#if __has_builtin(__builtin_amdgcn_mfma_f32_16x16x16_bf16)
#define PV_F16 0
__device__ __forceinline__ f32x4 mfma16(PV4 a, PV4 b, f32x4 c) {
  return __builtin_amdgcn_mfma_f32_16x16x16_bf16(a.b, b.b, c, 0, 0, 0);
}
#elif __has_builtin(__builtin_amdgcn_mfma_f32_16x16x16bf16_1k)
#define PV_F16 0
__device__ __forceinline__ f32x4 mfma16(PV4 a, PV4 b, f32x4 c) {
  return __builtin_amdgcn_mfma_f32_16x16x16bf16_1k(a.s, b.s, c, 0, 0, 0);
}
#else
#define PV_F16 1
__device__ __forceinline__ f32x4 mfma16(PV4 a, PV4 b, f32x4 c) {
  return __builtin_amdgcn_mfma_f32_16x16x16f16(a.f, b.f, c, 0, 0, 0);
}
#endif

__device__ __forceinline__ uint16_t pv_bits(__bf16 v) {
#if PV_F16
  union { _Float16 f; uint16_t u; } x; x.f = (_Float16)(float)v; return x.u;
#else
  union { __bf16 b; uint16_t u; } x; x.b = v; return x.u;
#endif
}

__device__ __forceinline__ PV4 pack4(float a, float b, float c, float d) {
  PV4 r;
#if PV_F16
  r.f = (f16x4){(_Float16)a, (_Float16)b, (_Float16)c, (_Float16)d};
#else
  r.b = (bf16x4){(__bf16)a, (__bf16)b, (__bf16)c, (__bf16)d};
#endif
  return r;
}

__device__ __forceinline__ void async_copy16(const void* g, void* l) {
  __builtin_amdgcn_global_load_lds(
      (const __attribute__((address_space(1))) void*)g,
      (__attribute__((address_space(3))) void*)l, 16, 0, 0);
}

// ---------------- fused fp32 -> bf16 cast of two buffers ----------------
__global__ __launch_bounds__(256) void k_cast2(const float* __restrict__ a,
    const float* __restrict__ b, __bf16* __restrict__ da,
    __bf16* __restrict__ db, int n) {
  int i = (blockIdx.x * 256 + threadIdx.x) * 4;
  const float* s = a; __bf16* d = da;
  if (i >= n) { s = b; d = db; i -= n; }
  float4 v = *(const float4*)(s + i);
  U64 o;
  o.h[0] = (__bf16)v.x; o.h[1] = (__bf16)v.y;
  o.h[2] = (__bf16)v.z; o.h[3] = (__bf16)v.w;
  *(uint2*)(d + i) = o.u;
}

// ---------------- pack up to 3 fp32 bias vectors (n each) into dst ----------------
__global__ __launch_bounds__(256) void k_pack(float* __restrict__ dst,
    const float* __restrict__ s0, const float* __restrict__ s1,
    const float* __restrict__ s2, int n) {
  int i = blockIdx.x * 256 + threadIdx.x;
  if (i < n) dst[i] = s0[i];
  else if (i < 2 * n) dst[i] = s1[i - n];
  else if (i < 3 * n) dst[i] = s2[i - 2 * n];
}

// ------------- batched 32x32 transpose + cast: src[z][R][C] f32 -> dst[z][C][R] bf16 -------------
__global__ __launch_bounds__(256) void k_transpose(const float* __restrict__ src,
    __bf16* __restrict__ dst, int R, int C) {
  __shared__ __bf16 tile[32][33];
  src += (size_t)blockIdx.z * R * C;
  dst += (size_t)blockIdx.z * R * C;
  int c0 = blockIdx.x * 32, r0 = blockIdx.y * 32;
  int tx = threadIdx.x & 31, ty = threadIdx.x >> 5;
  for (int i = ty; i < 32; i += 8)
    tile[i][tx] = (__bf16)src[(size_t)(r0 + i) * C + (c0 + tx)];
  __syncthreads();
  for (int i = ty; i < 32; i += 8)
    dst[(size_t)(c0 + i) * R + (r0 + tx)] = tile[tx][i];
}

// ------------- 3-source per-head transpose: srcN[16][R][C] f32 -> dst[z][C][R] bf16, z=src*16+head
__global__ __launch_bounds__(256) void k_transpose3(const float* __restrict__ s0,
    const float* __restrict__ s1, const float* __restrict__ s2,
    __bf16* __restrict__ dst, int R, int C) {
  __shared__ __bf16 tile[32][33];
  int z = blockIdx.z;
  const float* src = (z < 16) ? s0 : (z < 32) ? s1 : s2;
  src += (size_t)(z & 15) * R * C;
  dst += (size_t)z * R * C;
  int c0 = blockIdx.x * 32, r0 = blockIdx.y * 32;
  int tx = threadIdx.x & 31, ty = threadIdx.x >> 5;
  for (int i = ty; i < 32; i += 8)
    tile[i][tx] = (__bf16)src[(size_t)(r0 + i) * C + (c0 + tx)];
  __syncthreads();
  for (int i = ty; i < 32; i += 8)
    dst[(size_t)(c0 + i) * R + (r0 + tx)] = tile[tx][i];
}

// ---------------- bf16 TN GEMM: C[M,N] = A[M,K] * Bt[N,K]^T + bias ----------------
// 128x128 tile, BK=64, global_load_lds staging, 16B-granule XOR swizzle.
// T1: XCD-aware bijective block swizzle (all grids are multiples of 8 blocks) —
// each XCD gets a contiguous chunk of the linearized tile grid, so consecutive
// dispatches on one XCD cover adjacent N-tiles sharing the same A-panel in L2.
template<bool RELU, typename OutT>
__global__ __launch_bounds__(256, 3) void k_gemm(const __bf16* __restrict__ A,
    const __bf16* __restrict__ Bt, const float* __restrict__ bias,
    OutT* __restrict__ C, int M, int N, int K) {
  __shared__ __bf16 As[128][64];
  __shared__ __bf16 Bs[128][64];
  const int nbx = gridDim.x;
  const int id = blockIdx.y * nbx + blockIdx.x;
  const int chunk = (nbx * gridDim.y) >> 3;      // nwg % 8 == 0 for all our grids
  const int nid = (id & 7) * chunk + (id >> 3);
  const int m0 = (nid / nbx) * 128, n0 = (nid % nbx) * 128;
  const int t = threadIdx.x;
  const int wave = t >> 6, lane = t & 63;
  const int wm = (wave & 1) * 64, wn = (wave >> 1) * 64;
  const int lrow = lane & 15, quad = lane >> 4;
  const int r8 = lane >> 3;
  const int gG = (lane & 7) ^ (r8 & 7);
  const __bf16* Ap[4]; const __bf16* Bp[4];
  __bf16* lA[4]; __bf16* lB[4];
  for (int j = 0; j < 4; j++) {
    int rr = wave * 8 + j * 32 + r8;
    Ap[j] = A  + (size_t)(m0 + rr) * K + gG * 8;
    Bp[j] = Bt + (size_t)(n0 + rr) * K + gG * 8;
    lA[j] = &As[wave * 8 + j * 32][0];
    lB[j] = &Bs[wave * 8 + j * 32][0];
  }
  f32x4 acc[4][4] = {};
  for (int k0 = 0; k0 < K; k0 += 64) {
    __syncthreads();
    for (int j = 0; j < 4; j++) {
      async_copy16(Ap[j] + k0, lA[j]);
      async_copy16(Bp[j] + k0, lB[j]);
    }
    __syncthreads();
    for (int ks = 0; ks < 2; ks++) {
      bf16x8 af[4], bfv[4];
      for (int i = 0; i < 4; i++) {
        int ra = wm + i * 16 + lrow, rb = wn + i * 16 + lrow;
        af[i]  = *(const bf16x8*)&As[ra][(((ks * 4 + quad) ^ (ra & 7))) * 8];
        bfv[i] = *(const bf16x8*)&Bs[rb][(((ks * 4 + quad) ^ (rb & 7))) * 8];
      }
      for (int mi = 0; mi < 4; mi++)
        for (int ni = 0; ni < 4; ni++)
          acc[mi][ni] = __builtin_amdgcn_mfma_f32_16x16x32_bf16(af[mi], bfv[ni], acc[mi][ni], 0, 0, 0);
    }
  }
  for (int ni = 0; ni < 4; ni++) {
    int col = n0 + wn + ni * 16 + lrow;
    float bv = bias[col];
    for (int mi = 0; mi < 4; mi++) {
      int row = m0 + wm + mi * 16 + quad * 4;
      for (int r = 0; r < 4; r++) {
        float v = acc[mi][ni][r] + bv;
        if (RELU) v = fmaxf(v, 0.f);
        C[(size_t)(row + r) * N + col] = (OutT)v;
      }
    }
  }
}

// ---------------- fused flash attention v3: 2 q-tiles/block, S^T trick, register PV ----------
// grid (Lq/128, B*H). Causal: block bx covers q-tiles (bx, NT-1-bx) — compute-balanced pairing,
// fully-masked sub-tiles skipped via wave-uniform branch. Cross: tiles (2bx, 2bx+1).
// Each wave: 16 q-rows per tile. Softmax in exp2 domain (scale*log2e folded into Q).
// vs 653us baseline: l-sum cross-lane reduce deferred to epilogue (valid: alpha
// uniform across the 4-lane group since pm is group-reduced and m_r stays
// group-uniform), s_setprio(1) around MFMA clusters (T5).
// NOTE: do NOT hoist V^T frags out of the f-loop — vfr[4][4] (+128B/thread)
// spills to scratch under the (256,4) reg cap: round-2 showed +350MB HBM r/w,
// k_attn 101->231us. V reads from LDS per f are the cheaper form.
template<bool CAUSAL>
__global__ __launch_bounds__(256, 4) void k_attn(const __bf16* __restrict__ Q,
    const __bf16* __restrict__ Kg, const __bf16* __restrict__ Vg,
    float* __restrict__ O, int Lq, int Lk, int qs, int kvs) {
  __shared__ alignas(16) __bf16   Ks[2][64][72];
  __shared__ alignas(16) uint16_t Vt[2][64][72];   // [vd][k]
  const int t = threadIdx.x;
  const int wave = t >> 6, lane = t & 63;
  const int lrow = lane & 15, quad = lane >> 4;
  const int wm16 = wave * 16;
  int qt[2];
  if (CAUSAL) { qt[0] = blockIdx.x; qt[1] = gridDim.x * 2 - 1 - blockIdx.x; }
  else        { qt[0] = blockIdx.x * 2; qt[1] = qt[0] + 1; }
  const int b = blockIdx.y >> 4, h = blockIdx.y & 15;
  const __bf16* Qb = Q  + (size_t)b * Lq * qs  + h * DHEAD;
  const __bf16* Kb = Kg + (size_t)b * Lk * kvs + h * DHEAD;
  const __bf16* Vb = Vg + (size_t)b * Lk * kvs + h * DHEAD;
  // Q B-fragments, scale folded: 0.125 * log2(e) (softmax done in exp2 domain)
  const float qsc = 0.125f * 1.44269504f;
  bf16x8 qf[2][2];
  for (int f = 0; f < 2; f++)
    for (int ks = 0; ks < 2; ks++) {
      U128 u;
      u.u = *(const uint4*)(Qb + (size_t)(qt[f] * 64 + wm16 + lrow) * qs + ks * 32 + quad * 8);
      for (int j = 0; j < 8; j++) u.h[j] = (__bf16)((float)u.h[j] * qsc);
      qf[f][ks] = *(const bf16x8*)u.h;
    }
  const int nkt = CAUSAL ? (qt[1] + 1) : (Lk / 64);
  const int krow = t >> 3, kcol = (t & 7) * 8;
  const int vkk = t & 63;
  f32x4 acc_o[2][4] = {};       // O^T per frag: row vd=ni*16+quad*4+r, col q=lrow
  float m_r[2] = {-1e30f, -1e30f}, l_r[2] = {0.f, 0.f};
  uint4 ka, ka2, va, va2;
  ka  = *(const uint4*)(Kb + (size_t)krow * kvs + kcol);
  ka2 = *(const uint4*)(Kb + (size_t)(krow + 32) * kvs + kcol);
  va  = *(const uint4*)(Vb + (size_t)vkk * kvs + wave * 8);
  va2 = *(const uint4*)(Vb + (size_t)vkk * kvs + (wave + 4) * 8);
  int c = 0;
  for (int kt = 0; kt < nkt; kt++) {
    const int kn = (kt + 1 < nkt) ? (kt + 1) * 64 : kt * 64;
    uint4 na  = *(const uint4*)(Kb + (size_t)(kn + krow) * kvs + kcol);
    uint4 na2 = *(const uint4*)(Kb + (size_t)(kn + krow + 32) * kvs + kcol);
    uint4 nv  = *(const uint4*)(Vb + (size_t)(kn + vkk) * kvs + wave * 8);
    uint4 nv2 = *(const uint4*)(Vb + (size_t)(kn + vkk) * kvs + (wave + 4) * 8);
    *(uint4*)&Ks[c][krow][kcol]      = ka;
    *(uint4*)&Ks[c][krow + 32][kcol] = ka2;
    { U128 u; u.u = va;  for (int j = 0; j < 8; j++) Vt[c][wave * 8 + j][vkk] = pv_bits(u.h[j]); }
    { U128 u; u.u = va2; for (int j = 0; j < 8; j++) Vt[c][(wave + 4) * 8 + j][vkk] = pv_bits(u.h[j]); }
    __syncthreads();
    for (int f = 0; f < 2; f++) {
      if (CAUSAL && kt > qt[f]) continue;   // wave-uniform: fully-masked sub-tile
      // S^T = K Q^T : C-layout row k=nb*16+quad*4+r, col q=lrow  (exp2 domain)
      f32x4 st[4] = {};
      __builtin_amdgcn_s_setprio(1);
      for (int ks = 0; ks < 2; ks++)
        for (int nb = 0; nb < 4; nb++) {
          bf16x8 kf = *(const bf16x8*)&Ks[c][nb * 16 + lrow][ks * 32 + quad * 8];
          st[nb] = __builtin_amdgcn_mfma_f32_16x16x32_bf16(kf, qf[f][ks], st[nb], 0, 0, 0);
        }
      __builtin_amdgcn_s_setprio(0);
      float pm = -1e30f;
      for (int nb = 0; nb < 4; nb++)
        for (int r = 0; r < 4; r++) {
          float s = st[nb][r];
          if (CAUSAL && kt == qt[f])
            if (nb * 16 + quad * 4 + r > wm16 + lrow) s = -1e30f;
          st[nb][r] = s;
          pm = fmaxf(pm, s);
        }
      pm = fmaxf(pm, __shfl_xor(pm, 16));
      pm = fmaxf(pm, __shfl_xor(pm, 32));
      float mn = fmaxf(m_r[f], pm);
      float alpha = exp2f(m_r[f] - mn);
      m_r[f] = mn;
      float rs = 0.f;
      PV4 pf[4];
      for (int nb = 0; nb < 4; nb++) {
        float p0 = exp2f(st[nb][0] - mn), p1 = exp2f(st[nb][1] - mn);
        float p2 = exp2f(st[nb][2] - mn), p3 = exp2f(st[nb][3] - mn);
        rs += (p0 + p1) + (p2 + p3);
        pf[nb] = pack4(p0, p1, p2, p3);
      }
      l_r[f] = l_r[f] * alpha + rs;             // per-lane partial; reduced in epilogue
      for (int ni = 0; ni < 4; ni++)
        for (int r = 0; r < 4; r++) acc_o[f][ni][r] *= alpha;
      // O^T += V^T P^T  (A = V^T frag from LDS b64, B = P frag from registers)
      __builtin_amdgcn_s_setprio(1);
      for (int nb = 0; nb < 4; nb++)
        for (int ni = 0; ni < 4; ni++) {
          PV4 vf; vf.u = *(const uint2*)&Vt[c][ni * 16 + lrow][nb * 16 + quad * 4];
          acc_o[f][ni] = mfma16(vf, pf[nb], acc_o[f][ni]);
        }
      __builtin_amdgcn_s_setprio(0);
    }
    ka = na; ka2 = na2; va = nv; va2 = nv2;
    c ^= 1;
  }
  for (int f = 0; f < 2; f++) {
    float l = l_r[f];
    l += __shfl_xor(l, 16);
    l += __shfl_xor(l, 32);
    const float linv = 1.f / fmaxf(l, 1e-30f);
    float* orow = O + (size_t)b * Lq * DMODEL
                + (size_t)(qt[f] * 64 + wm16 + lrow) * DMODEL + h * DHEAD;
    for (int ni = 0; ni < 4; ni++) {
      float4 v = { acc_o[f][ni][0] * linv, acc_o[f][ni][1] * linv,
                   acc_o[f][ni][2] * linv, acc_o[f][ni][3] * linv };
      *(float4*)(orow + ni * 16 + quad * 4) = v;
    }
  }
}

// ---------------- residual(ResT + fp32) + LayerNorm -> OutT ----------------
template<typename ResT, typename OutT>
__global__ __launch_bounds__(256) void k_ln_add(const ResT* __restrict__ a,
    const float* __restrict__ bres, const float* __restrict__ g,
    const float* __restrict__ be, OutT* __restrict__ out) {
  __shared__ float red[2][4];
  const int r = blockIdx.x, t = threadIdx.x;
  const size_t base = (size_t)r * DMODEL + t * 4;
  float x[4];
  for (int i = 0; i < 4; i++) x[i] = (float)a[base + i] + bres[base + i];
  float s  = x[0] + x[1] + x[2] + x[3];
  float s2 = x[0]*x[0] + x[1]*x[1] + x[2]*x[2] + x[3]*x[3];
  for (int off = 32; off > 0; off >>= 1) {
    s  += __shfl_down(s, off);
    s2 += __shfl_down(s2, off);
  }
  if ((t & 63) == 0) { red[0][t >> 6] = s; red[1][t >> 6] = s2; }
  __syncthreads();
  s  = red[0][0] + red[0][1] + red[0][2] + red[0][3];
  s2 = red[1][0] + red[1][1] + red[1][2] + red[1][3];
  const float mean = s * (1.f / DMODEL);
  const float var  = s2 * (1.f / DMODEL) - mean * mean;
  const float rstd = rsqrtf(var + 1e-5f);
  for (int i = 0; i < 4; i++)
    out[base + i] = (OutT)((x[i] - mean) * rstd * g[t * 4 + i] + be[t * 4 + i]);
}

extern "C" void kernel_launch(void* const* d_in, const int* in_sizes, int n_in,
                              void* d_out, int out_size, void* d_ws, size_t ws_size,
                              hipStream_t stream) {
  (void)in_sizes; (void)n_in; (void)out_size; (void)ws_size;
  const float* dec   = (const float*)d_in[0];
  const float* enc   = (const float*)d_in[1];
  const float* m_wq  = (const float*)d_in[2];
  const float* m_bq  = (const float*)d_in[3];
  const float* m_wk  = (const float*)d_in[4];
  const float* m_bk  = (const float*)d_in[5];
  const float* m_wv  = (const float*)d_in[6];
  const float* m_bv  = (const float*)d_in[7];
  const float* c_wq  = (const float*)d_in[8];
  const float* c_bq  = (const float*)d_in[9];
  const float* c_wk  = (const float*)d_in[10];
  const float* c_bk  = (const float*)d_in[11];
  const float* c_wv  = (const float*)d_in[12];
  const float* c_bv  = (const float*)d_in[13];
  const float* ff_w1 = (const float*)d_in[14];
  const float* ff_b1 = (const float*)d_in[15];
  const float* ff_w2 = (const float*)d_in[16];
  const float* ff_b2 = (const float*)d_in[17];
  const float* ln1_g = (const float*)d_in[18];
  const float* ln1_b = (const float*)d_in[19];
  const float* ln2_g = (const float*)d_in[20];
  const float* ln2_b = (const float*)d_in[21];

  // workspace (136 MB):
  //  [0,16)   decB -> X1b          [16,32)  encB -> X2b
  //  [32,40)  WB weights (bf16); fp32 bias pack at +38MB
  //  [40,88)  QKV (self) | [40,72) KV (cross) + [72,88) Qc | [40,104) FF
  //  [104,136) AO (fp32)
  char* w = (char*)d_ws;
  __bf16* decB = (__bf16*)(w);
  __bf16* encB = (__bf16*)(w + (16ull << 20));
  __bf16* X1b  = decB;
  __bf16* X2b  = encB;
  __bf16* WB   = (__bf16*)(w + (32ull << 20));
  float*  BP   = (float*) (w + (38ull << 20));
  __bf16* QKV  = (__bf16*)(w + (40ull << 20));
  __bf16* KV   = (__bf16*)(w + (40ull << 20));
  __bf16* Qc   = (__bf16*)(w + (72ull << 20));
  __bf16* FF   = (__bf16*)(w + (40ull << 20));
  float*  AO   = (float*) (w + (104ull << 20));
  float* out = (float*)d_out;

  const int M = 8192, NTOK = M * DMODEL;
  dim3 blk(256);
  dim3 gT3(2, 32, 48);    // 3-source per-head weight transpose
  dim3 gA(8, 128);        // attention: 2 q-tiles per block
  dim3 gL(M);

  k_cast2<<<dim3(2 * NTOK / 1024), blk, 0, stream>>>(dec, enc, decB, encB, NTOK);

  // ---- masked self-attention: fused QKV projection (N=3072) ----
  k_transpose3<<<gT3, blk, 0, stream>>>(m_wq, m_wk, m_wv, WB, 1024, 64);
  k_pack<<<dim3(12), blk, 0, stream>>>(BP, m_bq, m_bk, m_bv, 1024);
  k_gemm<false, __bf16><<<dim3(24, 64), blk, 0, stream>>>(decB, WB, BP, QKV, M, 3072, 1024);
  k_attn<true><<<gA, blk, 0, stream>>>(QKV, QKV + 1024, QKV + 2048, AO, 1024, 1024, 3072, 3072);
  k_ln_add<float, __bf16><<<gL, blk, 0, stream>>>(dec, AO, ln1_g, ln1_b, X1b);  // decB dead

  // ---- cross-attention: fused KV (N=2048, enc) + Q (X1b) ----
  k_transpose3<<<gT3, blk, 0, stream>>>(c_wk, c_wv, c_wq, WB, 1024, 64);
  k_pack<<<dim3(8), blk, 0, stream>>>(BP, c_bk, c_bv, c_bv, 1024);
  k_gemm<false, __bf16><<<dim3(16, 64), blk, 0, stream>>>(encB, WB, BP, KV, M, 2048, 1024);
  k_gemm<false, __bf16><<<dim3(8, 64), blk, 0, stream>>>(X1b, WB + (2 << 20), c_bq, Qc, M, 1024, 1024);
  k_attn<false><<<gA, blk, 0, stream>>>(Qc, KV, KV + 1024, AO, 1024, 1024, 1024, 2048);
  k_ln_add<__bf16, __bf16><<<gL, blk, 0, stream>>>(X1b, AO, ln2_g, ln2_b, X2b);  // encB dead

  // ---- FFN (QKV/KV/Qc dead -> FF overlays [40,104)) ----
  k_transpose<<<dim3(128, 32, 1), blk, 0, stream>>>(ff_w1, WB, 1024, 4096);
  k_gemm<true, __bf16><<<dim3(32, 64), blk, 0, stream>>>(X2b, WB, ff_b1, FF, M, 4096, 1024);
  k_transpose<<<dim3(32, 128, 1), blk, 0, stream>>>(ff_w2, WB, 4096, 1024);
  k_gemm<false, float><<<dim3(8, 64), blk, 0, stream>>>(FF, WB, ff_b2, AO, M, 1024, 4096);
  k_ln_add<__bf16, float><<<gL, blk, 0, stream>>>(X2b, AO, ln2_g, ln2_b, out);
}

// Round 4
// 684.392 us; speedup vs baseline: 1.1750x; 1.0595x over previous
//
#include <hip/hip_runtime.h>
#include <hip/hip_bf16.h>
#include <cstdint>

typedef __bf16 bf16x8 __attribute__((ext_vector_type(8)));
typedef __bf16 bf16x4 __attribute__((ext_vector_type(4)));
typedef short  short4v __attribute__((ext_vector_type(4)));
typedef _Float16 f16x4 __attribute__((ext_vector_type(4)));
typedef float f32x4 __attribute__((ext_vector_type(4)));

union U128 { uint4 u; __bf16 h[8]; };
union U64  { uint2 u; __bf16 h[4]; };
union PV4  { uint2 u; bf16x4 b; short4v s; f16x4 f; };

#define DMODEL 1024
#define NHEAD  16
#define DHEAD  64

// ---- 16x16x16 MFMA selection for the PV step (P/V as 4x16-bit per lane) ----
#if __has_builtin(__builtin_amdgcn_mfma_f32_16x16x16_bf16)
#define PV_F16 0
__device__ __forceinline__ f32x4 mfma16(PV4 a, PV4 b, f32x4 c) {
  return __builtin_amdgcn_mfma_f32_16x16x16_bf16(a.b, b.b, c, 0, 0, 0);
}
#elif __has_builtin(__builtin_amdgcn_mfma_f32_16x16x16bf16_1k)
#define PV_F16 0
__device__ __forceinline__ f32x4 mfma16(PV4 a, PV4 b, f32x4 c) {
  return __builtin_amdgcn_mfma_f32_16x16x16bf16_1k(a.s, b.s, c, 0, 0, 0);
}
#else
#define PV_F16 1
__device__ __forceinline__ f32x4 mfma16(PV4 a, PV4 b, f32x4 c) {
  return __builtin_amdgcn_mfma_f32_16x16x16f16(a.f, b.f, c, 0, 0, 0);
}
#endif

__device__ __forceinline__ uint16_t pv_bits(__bf16 v) {
#if PV_F16
  union { _Float16 f; uint16_t u; } x; x.f = (_Float16)(float)v; return x.u;
#else
  union { __bf16 b; uint16_t u; } x; x.b = v; return x.u;
#endif
}

__device__ __forceinline__ PV4 pack4(float a, float b, float c, float d) {
  PV4 r;
#if PV_F16
  r.f = (f16x4){(_Float16)a, (_Float16)b, (_Float16)c, (_Float16)d};
#else
  r.b = (bf16x4){(__bf16)a, (__bf16)b, (__bf16)c, (__bf16)d};
#endif
  return r;
}

__device__ __forceinline__ void async_copy16(const void* g, void* l) {
  __builtin_amdgcn_global_load_lds(
      (const __attribute__((address_space(1))) void*)g,
      (__attribute__((address_space(3))) void*)l, 16, 0, 0);
}

// ---------------- fused fp32 -> bf16 cast of two buffers ----------------
__global__ __launch_bounds__(256) void k_cast2(const float* __restrict__ a,
    const float* __restrict__ b, __bf16* __restrict__ da,
    __bf16* __restrict__ db, int n) {
  int i = (blockIdx.x * 256 + threadIdx.x) * 4;
  const float* s = a; __bf16* d = da;
  if (i >= n) { s = b; d = db; i -= n; }
  float4 v = *(const float4*)(s + i);
  U64 o;
  o.h[0] = (__bf16)v.x; o.h[1] = (__bf16)v.y;
  o.h[2] = (__bf16)v.z; o.h[3] = (__bf16)v.w;
  *(uint2*)(d + i) = o.u;
}

// ---------------- pack up to 3 fp32 bias vectors (n each) into dst ----------------
__global__ __launch_bounds__(256) void k_pack(float* __restrict__ dst,
    const float* __restrict__ s0, const float* __restrict__ s1,
    const float* __restrict__ s2, int n) {
  int i = blockIdx.x * 256 + threadIdx.x;
  if (i < n) dst[i] = s0[i];
  else if (i < 2 * n) dst[i] = s1[i - n];
  else if (i < 3 * n) dst[i] = s2[i - 2 * n];
}

// ------------- batched 32x32 transpose + cast: src[z][R][C] f32 -> dst[z][C][R] bf16 -------------
__global__ __launch_bounds__(256) void k_transpose(const float* __restrict__ src,
    __bf16* __restrict__ dst, int R, int C) {
  __shared__ __bf16 tile[32][33];
  src += (size_t)blockIdx.z * R * C;
  dst += (size_t)blockIdx.z * R * C;
  int c0 = blockIdx.x * 32, r0 = blockIdx.y * 32;
  int tx = threadIdx.x & 31, ty = threadIdx.x >> 5;
  for (int i = ty; i < 32; i += 8)
    tile[i][tx] = (__bf16)src[(size_t)(r0 + i) * C + (c0 + tx)];
  __syncthreads();
  for (int i = ty; i < 32; i += 8)
    dst[(size_t)(c0 + i) * R + (r0 + tx)] = tile[tx][i];
}

// ------------- 3-source per-head transpose: srcN[16][R][C] f32 -> dst[z][C][R] bf16, z=src*16+head
__global__ __launch_bounds__(256) void k_transpose3(const float* __restrict__ s0,
    const float* __restrict__ s1, const float* __restrict__ s2,
    __bf16* __restrict__ dst, int R, int C) {
  __shared__ __bf16 tile[32][33];
  int z = blockIdx.z;
  const float* src = (z < 16) ? s0 : (z < 32) ? s1 : s2;
  src += (size_t)(z & 15) * R * C;
  dst += (size_t)z * R * C;
  int c0 = blockIdx.x * 32, r0 = blockIdx.y * 32;
  int tx = threadIdx.x & 31, ty = threadIdx.x >> 5;
  for (int i = ty; i < 32; i += 8)
    tile[i][tx] = (__bf16)src[(size_t)(r0 + i) * C + (c0 + tx)];
  __syncthreads();
  for (int i = ty; i < 32; i += 8)
    dst[(size_t)(c0 + i) * R + (r0 + tx)] = tile[tx][i];
}

// ---------------- bf16 TN GEMM: C[M,N] = A[M,K] * Bt[N,K]^T + bias ----------------
// 128x128 tile, BK=64, global_load_lds staging, 16B-granule XOR swizzle.
// T1: XCD-aware bijective block swizzle (all grids are multiples of 8 blocks) —
// each XCD gets a contiguous chunk of the linearized tile grid, so consecutive
// blocks on one XCD cover adjacent tiles sharing A/B panels in that XCD's L2.
// (Correctness of the remap proven in round 3: passed absmax 0.03125.)
template<bool RELU, typename OutT>
__global__ __launch_bounds__(256, 3) void k_gemm(const __bf16* __restrict__ A,
    const __bf16* __restrict__ Bt, const float* __restrict__ bias,
    OutT* __restrict__ C, int M, int N, int K) {
  __shared__ __bf16 As[128][64];
  __shared__ __bf16 Bs[128][64];
  const int nbx = gridDim.x;
  const int id = blockIdx.y * nbx + blockIdx.x;
  const int chunk = (nbx * gridDim.y) >> 3;      // nwg % 8 == 0 for all our grids
  const int nid = (id & 7) * chunk + (id >> 3);
  const int m0 = (nid / nbx) * 128, n0 = (nid % nbx) * 128;
  const int t = threadIdx.x;
  const int wave = t >> 6, lane = t & 63;
  const int wm = (wave & 1) * 64, wn = (wave >> 1) * 64;
  const int lrow = lane & 15, quad = lane >> 4;
  const int r8 = lane >> 3;
  const int gG = (lane & 7) ^ (r8 & 7);
  const __bf16* Ap[4]; const __bf16* Bp[4];
  __bf16* lA[4]; __bf16* lB[4];
  for (int j = 0; j < 4; j++) {
    int rr = wave * 8 + j * 32 + r8;
    Ap[j] = A  + (size_t)(m0 + rr) * K + gG * 8;
    Bp[j] = Bt + (size_t)(n0 + rr) * K + gG * 8;
    lA[j] = &As[wave * 8 + j * 32][0];
    lB[j] = &Bs[wave * 8 + j * 32][0];
  }
  f32x4 acc[4][4] = {};
  for (int k0 = 0; k0 < K; k0 += 64) {
    __syncthreads();
    for (int j = 0; j < 4; j++) {
      async_copy16(Ap[j] + k0, lA[j]);
      async_copy16(Bp[j] + k0, lB[j]);
    }
    __syncthreads();
    for (int ks = 0; ks < 2; ks++) {
      bf16x8 af[4], bfv[4];
      for (int i = 0; i < 4; i++) {
        int ra = wm + i * 16 + lrow, rb = wn + i * 16 + lrow;
        af[i]  = *(const bf16x8*)&As[ra][(((ks * 4 + quad) ^ (ra & 7))) * 8];
        bfv[i] = *(const bf16x8*)&Bs[rb][(((ks * 4 + quad) ^ (rb & 7))) * 8];
      }
      for (int mi = 0; mi < 4; mi++)
        for (int ni = 0; ni < 4; ni++)
          acc[mi][ni] = __builtin_amdgcn_mfma_f32_16x16x32_bf16(af[mi], bfv[ni], acc[mi][ni], 0, 0, 0);
    }
  }
  for (int ni = 0; ni < 4; ni++) {
    int col = n0 + wn + ni * 16 + lrow;
    float bv = bias[col];
    for (int mi = 0; mi < 4; mi++) {
      int row = m0 + wm + mi * 16 + quad * 4;
      for (int r = 0; r < 4; r++) {
        float v = acc[mi][ni][r] + bv;
        if (RELU) v = fmaxf(v, 0.f);
        C[(size_t)(row + r) * N + col] = (OutT)v;
      }
    }
  }
}

// ---------------- fused flash attention v3: 2 q-tiles/block, S^T trick, register PV ----------
// grid (Lq/128, B*H). Causal: block bx covers q-tiles (bx, NT-1-bx) — compute-balanced pairing,
// fully-masked sub-tiles skipped via wave-uniform branch. Cross: tiles (2bx, 2bx+1).
// Each wave: 16 q-rows per tile. Softmax in exp2 domain (scale*log2e folded into Q).
// PERF LEDGER (do not re-try without fixing the spill mechanism):
//  - vfr[4][4] V-frag hoist across f: +128B/thread live -> scratch spill,
//    +350MB HBM r/w, k_attn 101->231us (round 2).
//  - s_setprio(1/0) around MFMA clusters: code-motion barrier keeps st[4]/pf
//    live across region boundaries under the (256,4) 128-VGPR cap -> st spills,
//    +260MB HBM r/w, k_attn 101->162us (round 3). This kernel is AT the register
//    cap; any scheduling constraint or added live range spills.
template<bool CAUSAL>
__global__ __launch_bounds__(256, 4) void k_attn(const __bf16* __restrict__ Q,
    const __bf16* __restrict__ Kg, const __bf16* __restrict__ Vg,
    float* __restrict__ O, int Lq, int Lk, int qs, int kvs) {
  __shared__ alignas(16) __bf16   Ks[2][64][72];
  __shared__ alignas(16) uint16_t Vt[2][64][72];   // [vd][k]
  const int t = threadIdx.x;
  const int wave = t >> 6, lane = t & 63;
  const int lrow = lane & 15, quad = lane >> 4;
  const int wm16 = wave * 16;
  int qt[2];
  if (CAUSAL) { qt[0] = blockIdx.x; qt[1] = gridDim.x * 2 - 1 - blockIdx.x; }
  else        { qt[0] = blockIdx.x * 2; qt[1] = qt[0] + 1; }
  const int b = blockIdx.y >> 4, h = blockIdx.y & 15;
  const __bf16* Qb = Q  + (size_t)b * Lq * qs  + h * DHEAD;
  const __bf16* Kb = Kg + (size_t)b * Lk * kvs + h * DHEAD;
  const __bf16* Vb = Vg + (size_t)b * Lk * kvs + h * DHEAD;
  // Q B-fragments, scale folded: 0.125 * log2(e) (softmax done in exp2 domain)
  const float qsc = 0.125f * 1.44269504f;
  bf16x8 qf[2][2];
  for (int f = 0; f < 2; f++)
    for (int ks = 0; ks < 2; ks++) {
      U128 u;
      u.u = *(const uint4*)(Qb + (size_t)(qt[f] * 64 + wm16 + lrow) * qs + ks * 32 + quad * 8);
      for (int j = 0; j < 8; j++) u.h[j] = (__bf16)((float)u.h[j] * qsc);
      qf[f][ks] = *(const bf16x8*)u.h;
    }
  const int nkt = CAUSAL ? (qt[1] + 1) : (Lk / 64);
  const int krow = t >> 3, kcol = (t & 7) * 8;
  const int vkk = t & 63;
  f32x4 acc_o[2][4] = {};       // O^T per frag: row vd=ni*16+quad*4+r, col q=lrow
  float m_r[2] = {-1e30f, -1e30f}, l_r[2] = {0.f, 0.f};
  uint4 ka, ka2, va, va2;
  ka  = *(const uint4*)(Kb + (size_t)krow * kvs + kcol);
  ka2 = *(const uint4*)(Kb + (size_t)(krow + 32) * kvs + kcol);
  va  = *(const uint4*)(Vb + (size_t)vkk * kvs + wave * 8);
  va2 = *(const uint4*)(Vb + (size_t)vkk * kvs + (wave + 4) * 8);
  int c = 0;
  for (int kt = 0; kt < nkt; kt++) {
    const int kn = (kt + 1 < nkt) ? (kt + 1) * 64 : kt * 64;
    uint4 na  = *(const uint4*)(Kb + (size_t)(kn + krow) * kvs + kcol);
    uint4 na2 = *(const uint4*)(Kb + (size_t)(kn + krow + 32) * kvs + kcol);
    uint4 nv  = *(const uint4*)(Vb + (size_t)(kn + vkk) * kvs + wave * 8);
    uint4 nv2 = *(const uint4*)(Vb + (size_t)(kn + vkk) * kvs + (wave + 4) * 8);
    *(uint4*)&Ks[c][krow][kcol]      = ka;
    *(uint4*)&Ks[c][krow + 32][kcol] = ka2;
    { U128 u; u.u = va;  for (int j = 0; j < 8; j++) Vt[c][wave * 8 + j][vkk] = pv_bits(u.h[j]); }
    { U128 u; u.u = va2; for (int j = 0; j < 8; j++) Vt[c][(wave + 4) * 8 + j][vkk] = pv_bits(u.h[j]); }
    __syncthreads();
    for (int f = 0; f < 2; f++) {
      if (CAUSAL && kt > qt[f]) continue;   // wave-uniform: fully-masked sub-tile
      // S^T = K Q^T : C-layout row k=nb*16+quad*4+r, col q=lrow  (exp2 domain)
      f32x4 st[4] = {};
      for (int ks = 0; ks < 2; ks++)
        for (int nb = 0; nb < 4; nb++) {
          bf16x8 kf = *(const bf16x8*)&Ks[c][nb * 16 + lrow][ks * 32 + quad * 8];
          st[nb] = __builtin_amdgcn_mfma_f32_16x16x32_bf16(kf, qf[f][ks], st[nb], 0, 0, 0);
        }
      float pm = -1e30f;
      for (int nb = 0; nb < 4; nb++)
        for (int r = 0; r < 4; r++) {
          float s = st[nb][r];
          if (CAUSAL && kt == qt[f])
            if (nb * 16 + quad * 4 + r > wm16 + lrow) s = -1e30f;
          st[nb][r] = s;
          pm = fmaxf(pm, s);
        }
      pm = fmaxf(pm, __shfl_xor(pm, 16));
      pm = fmaxf(pm, __shfl_xor(pm, 32));
      float mn = fmaxf(m_r[f], pm);
      float alpha = exp2f(m_r[f] - mn);
      m_r[f] = mn;
      float rs = 0.f;
      PV4 pf[4];
      for (int nb = 0; nb < 4; nb++) {
        float p0 = exp2f(st[nb][0] - mn), p1 = exp2f(st[nb][1] - mn);
        float p2 = exp2f(st[nb][2] - mn), p3 = exp2f(st[nb][3] - mn);
        rs += (p0 + p1) + (p2 + p3);
        pf[nb] = pack4(p0, p1, p2, p3);
      }
      rs += __shfl_xor(rs, 16);
      rs += __shfl_xor(rs, 32);
      l_r[f] = l_r[f] * alpha + rs;
      for (int ni = 0; ni < 4; ni++)
        for (int r = 0; r < 4; r++) acc_o[f][ni][r] *= alpha;
      // O^T += V^T P^T  (A = V^T frag from LDS b64, B = P frag from registers)
      for (int nb = 0; nb < 4; nb++)
        for (int ni = 0; ni < 4; ni++) {
          PV4 vf; vf.u = *(const uint2*)&Vt[c][ni * 16 + lrow][nb * 16 + quad * 4];
          acc_o[f][ni] = mfma16(vf, pf[nb], acc_o[f][ni]);
        }
    }
    ka = na; ka2 = na2; va = nv; va2 = nv2;
    c ^= 1;
  }
  for (int f = 0; f < 2; f++) {
    const float linv = 1.f / fmaxf(l_r[f], 1e-30f);
    float* orow = O + (size_t)b * Lq * DMODEL
                + (size_t)(qt[f] * 64 + wm16 + lrow) * DMODEL + h * DHEAD;
    for (int ni = 0; ni < 4; ni++) {
      float4 v = { acc_o[f][ni][0] * linv, acc_o[f][ni][1] * linv,
                   acc_o[f][ni][2] * linv, acc_o[f][ni][3] * linv };
      *(float4*)(orow + ni * 16 + quad * 4) = v;
    }
  }
}

// ---------------- residual(ResT + fp32) + LayerNorm -> OutT ----------------
template<typename ResT, typename OutT>
__global__ __launch_bounds__(256) void k_ln_add(const ResT* __restrict__ a,
    const float* __restrict__ bres, const float* __restrict__ g,
    const float* __restrict__ be, OutT* __restrict__ out) {
  __shared__ float red[2][4];
  const int r = blockIdx.x, t = threadIdx.x;
  const size_t base = (size_t)r * DMODEL + t * 4;
  float x[4];
  for (int i = 0; i < 4; i++) x[i] = (float)a[base + i] + bres[base + i];
  float s  = x[0] + x[1] + x[2] + x[3];
  float s2 = x[0]*x[0] + x[1]*x[1] + x[2]*x[2] + x[3]*x[3];
  for (int off = 32; off > 0; off >>= 1) {
    s  += __shfl_down(s, off);
    s2 += __shfl_down(s2, off);
  }
  if ((t & 63) == 0) { red[0][t >> 6] = s; red[1][t >> 6] = s2; }
  __syncthreads();
  s  = red[0][0] + red[0][1] + red[0][2] + red[0][3];
  s2 = red[1][0] + red[1][1] + red[1][2] + red[1][3];
  const float mean = s * (1.f / DMODEL);
  const float var  = s2 * (1.f / DMODEL) - mean * mean;
  const float rstd = rsqrtf(var + 1e-5f);
  for (int i = 0; i < 4; i++)
    out[base + i] = (OutT)((x[i] - mean) * rstd * g[t * 4 + i] + be[t * 4 + i]);
}

extern "C" void kernel_launch(void* const* d_in, const int* in_sizes, int n_in,
                              void* d_out, int out_size, void* d_ws, size_t ws_size,
                              hipStream_t stream) {
  (void)in_sizes; (void)n_in; (void)out_size; (void)ws_size;
  const float* dec   = (const float*)d_in[0];
  const float* enc   = (const float*)d_in[1];
  const float* m_wq  = (const float*)d_in[2];
  const float* m_bq  = (const float*)d_in[3];
  const float* m_wk  = (const float*)d_in[4];
  const float* m_bk  = (const float*)d_in[5];
  const float* m_wv  = (const float*)d_in[6];
  const float* m_bv  = (const float*)d_in[7];
  const float* c_wq  = (const float*)d_in[8];
  const float* c_bq  = (const float*)d_in[9];
  const float* c_wk  = (const float*)d_in[10];
  const float* c_bk  = (const float*)d_in[11];
  const float* c_wv  = (const float*)d_in[12];
  const float* c_bv  = (const float*)d_in[13];
  const float* ff_w1 = (const float*)d_in[14];
  const float* ff_b1 = (const float*)d_in[15];
  const float* ff_w2 = (const float*)d_in[16];
  const float* ff_b2 = (const float*)d_in[17];
  const float* ln1_g = (const float*)d_in[18];
  const float* ln1_b = (const float*)d_in[19];
  const float* ln2_g = (const float*)d_in[20];
  const float* ln2_b = (const float*)d_in[21];

  // workspace (136 MB):
  //  [0,16)   decB -> X1b          [16,32)  encB -> X2b
  //  [32,40)  WB weights (bf16); fp32 bias pack at +38MB
  //  [40,88)  QKV (self) | [40,72) KV (cross) + [72,88) Qc | [40,104) FF
  //  [104,136) AO (fp32)
  char* w = (char*)d_ws;
  __bf16* decB = (__bf16*)(w);
  __bf16* encB = (__bf16*)(w + (16ull << 20));
  __bf16* X1b  = decB;
  __bf16* X2b  = encB;
  __bf16* WB   = (__bf16*)(w + (32ull << 20));
  float*  BP   = (float*) (w + (38ull << 20));
  __bf16* QKV  = (__bf16*)(w + (40ull << 20));
  __bf16* KV   = (__bf16*)(w + (40ull << 20));
  __bf16* Qc   = (__bf16*)(w + (72ull << 20));
  __bf16* FF   = (__bf16*)(w + (40ull << 20));
  float*  AO   = (float*) (w + (104ull << 20));
  float* out = (float*)d_out;

  const int M = 8192, NTOK = M * DMODEL;
  dim3 blk(256);
  dim3 gT3(2, 32, 48);    // 3-source per-head weight transpose
  dim3 gA(8, 128);        // attention: 2 q-tiles per block
  dim3 gL(M);

  k_cast2<<<dim3(2 * NTOK / 1024), blk, 0, stream>>>(dec, enc, decB, encB, NTOK);

  // ---- masked self-attention: fused QKV projection (N=3072) ----
  k_transpose3<<<gT3, blk, 0, stream>>>(m_wq, m_wk, m_wv, WB, 1024, 64);
  k_pack<<<dim3(12), blk, 0, stream>>>(BP, m_bq, m_bk, m_bv, 1024);
  k_gemm<false, __bf16><<<dim3(24, 64), blk, 0, stream>>>(decB, WB, BP, QKV, M, 3072, 1024);
  k_attn<true><<<gA, blk, 0, stream>>>(QKV, QKV + 1024, QKV + 2048, AO, 1024, 1024, 3072, 3072);
  k_ln_add<float, __bf16><<<gL, blk, 0, stream>>>(dec, AO, ln1_g, ln1_b, X1b);  // decB dead

  // ---- cross-attention: fused KV (N=2048, enc) + Q (X1b) ----
  k_transpose3<<<gT3, blk, 0, stream>>>(c_wk, c_wv, c_wq, WB, 1024, 64);
  k_pack<<<dim3(8), blk, 0, stream>>>(BP, c_bk, c_bv, c_bv, 1024);
  k_gemm<false, __bf16><<<dim3(16, 64), blk, 0, stream>>>(encB, WB, BP, KV, M, 2048, 1024);
  k_gemm<false, __bf16><<<dim3(8, 64), blk, 0, stream>>>(X1b, WB + (2 << 20), c_bq, Qc, M, 1024, 1024);
  k_attn<false><<<gA, blk, 0, stream>>>(Qc, KV, KV + 1024, AO, 1024, 1024, 1024, 2048);
  k_ln_add<__bf16, __bf16><<<gL, blk, 0, stream>>>(X1b, AO, ln2_g, ln2_b, X2b);  // encB dead

  // ---- FFN (QKV/KV/Qc dead -> FF overlays [40,104)) ----
  k_transpose<<<dim3(128, 32, 1), blk, 0, stream>>>(ff_w1, WB, 1024, 4096);
  k_gemm<true, __bf16><<<dim3(32, 64), blk, 0, stream>>>(X2b, WB, ff_b1, FF, M, 4096, 1024);
  k_transpose<<<dim3(32, 128, 1), blk, 0, stream>>>(ff_w2, WB, 4096, 1024);
  k_gemm<false, float><<<dim3(8, 64), blk, 0, stream>>>(FF, WB, ff_b2, AO, M, 1024, 4096);
  k_ln_add<__bf16, float><<<gL, blk, 0, stream>>>(X2b, AO, ln2_g, ln2_b, out);
}